// Round 2
// baseline (1645.561 us; speedup 1.0000x reference)
//
#include <hip/hip_runtime.h>
#include <hip/hip_bf16.h>
#include <hip/hip_fp16.h>
#include <math.h>

#define EPSF 1e-5f

// ---------------- init: f = bias rows, zero xmom ----------------
__global__ void k_init(float* __restrict__ f, const float* __restrict__ bfc1,
                       const float* __restrict__ bfc2, float* __restrict__ xmom) {
  int t = blockIdx.x * 256 + threadIdx.x;  // 65536 total
  int col = t & 255;
  f[t] = (col < 128) ? bfc1[col] : bfc2[col & 127];
  if (t < 32) xmom[t] = 0.f;
}

// ---------------- K1: second moments of x per net ----------------
__global__ __launch_bounds__(256) void k_xmom(const float* __restrict__ x, float* __restrict__ xmom) {
  int b = blockIdx.x, t = threadIdx.x;
  const float* xr = x + (size_t)b * 6144;
  for (int net = 0; net < 2; ++net) {
    float a[9] = {0,0,0,0,0,0,0,0,0};
    const float* xn = xr + net * 3072;
    for (int p = t; p < 1024; p += 256) {
      float x0 = xn[3*p], x1 = xn[3*p+1], x2 = xn[3*p+2];
      a[0]+=x0; a[1]+=x1; a[2]+=x2;
      a[3]+=x0*x0; a[4]+=x0*x1; a[5]+=x0*x2;
      a[6]+=x1*x1; a[7]+=x1*x2; a[8]+=x2*x2;
    }
    #pragma unroll
    for (int i = 0; i < 9; ++i) {
      float v = a[i];
      #pragma unroll
      for (int m = 1; m < 64; m <<= 1) v += __shfl_xor(v, m, 64);
      if ((t & 63) == 0) atomicAdd(&xmom[net*16 + i], v);
    }
  }
}

// ---------------- K2: BN1 channel params (eps', sign) ----------------
__global__ void k_bn1(const float* __restrict__ xmom,
                      const float* __restrict__ win1, const float* __restrict__ bin1, const float* __restrict__ g11,
                      const float* __restrict__ win2, const float* __restrict__ bin2, const float* __restrict__ g12,
                      float* __restrict__ bn1) {
  int t = threadIdx.x; int net = t >> 7, c = t & 127;
  const float* win = net ? win2 : win1;
  const float* bin = net ? bin2 : bin1;
  const float* g   = net ? g12  : g11;
  const float* m = xmom + net * 16;
  const float inv = 1.f / (256.f * 1024.f);
  float w0 = win[3*c], w1 = win[3*c+1], w2 = win[3*c+2], bi = bin[c];
  float s0 = m[0]*inv, s1 = m[1]*inv, s2 = m[2]*inv;
  float lin = w0*s0 + w1*s1 + w2*s2;
  float mean = lin + bi;
  float e2 = (w0*w0*m[3] + 2.f*w0*w1*m[4] + 2.f*w0*w2*m[5] + w1*w1*m[6] + 2.f*w1*w2*m[7] + w2*w2*m[8]) * inv
             + 2.f*bi*lin + bi*bi;
  float var = fmaxf(e2 - mean*mean, 0.f);
  float gc = g[c];
  float aa = gc*gc / (var + EPSF);   // a^2 for bn scale a = g*rsqrt(var+eps)
  float sgn = (gc > 0.f) ? 1.f : ((gc < 0.f) ? -1.f : 0.f);
  float epsp = (aa > 0.f) ? (EPSF / aa) : 1.f;  // if g==0, sgn=0 makes output 0 anyway
  bn1[2*(net*128+c)]   = epsp;
  bn1[2*(net*128+c)+1] = sgn;
}

// ---------------- K3: h1 = relu(inorm(bn1(W_in x))) -> fp16 ----------------
__global__ __launch_bounds__(256) void k_h1(const float* __restrict__ x,
    const float* __restrict__ win1, const float* __restrict__ bin1,
    const float* __restrict__ win2, const float* __restrict__ bin2,
    const float* __restrict__ bn1, __half* __restrict__ h1) {
  int blk = blockIdx.x; int net = blk >> 8, b = blk & 255;
  int t = threadIdx.x, wid = t >> 6, lane = t & 63;
  __shared__ float xs[3072];
  const float4* xr = (const float4*)(x + (size_t)b*6144 + net*3072);
  float4* xsv = (float4*)xs;
  for (int i = t; i < 768; i += 256) xsv[i] = xr[i];
  __syncthreads();
  const float* win = net ? win2 : win1;
  const float* bin = net ? bin2 : bin1;
  __half* out = h1 + (size_t)(net*256 + b) * 131072;
  for (int c = wid; c < 128; c += 4) {
    float w0 = win[3*c], w1 = win[3*c+1], w2 = win[3*c+2], bi = bin[c];
    float h[16];
    float s = 0.f, ss = 0.f;
    #pragma unroll
    for (int j = 0; j < 8; ++j) {
      int base = 6*lane + 384*j;   // p0 = 2*lane + 128*j
      float2 d0 = *(const float2*)&xs[base];
      float2 d1 = *(const float2*)&xs[base+2];
      float2 d2 = *(const float2*)&xs[base+4];
      float v0 = w0*d0.x + w1*d0.y + w2*d1.x + bi;
      float v1 = w0*d1.y + w1*d2.x + w2*d2.y + bi;
      h[2*j] = v0; h[2*j+1] = v1;
      s += v0 + v1; ss += v0*v0 + v1*v1;
    }
    #pragma unroll
    for (int m = 1; m < 64; m <<= 1) { s += __shfl_xor(s, m, 64); ss += __shfl_xor(ss, m, 64); }
    float mean = s * (1.f/1024.f);
    float var  = fmaxf(ss * (1.f/1024.f) - mean*mean, 0.f);
    float epsp = bn1[2*(net*128+c)], sgn = bn1[2*(net*128+c)+1];
    float isd = sgn * rsqrtf(var + epsp);
    #pragma unroll
    for (int j = 0; j < 8; ++j) {
      float r0 = fmaxf((h[2*j]   - mean)*isd, 0.f);
      float r1 = fmaxf((h[2*j+1] - mean)*isd, 0.f);
      *(__half2*)(out + (size_t)c*1024 + 2*lane + 128*j) = __floats2half2_rn(r0, r1);
    }
  }
}

// ---------------- K4a: h2 = W_c h1 + b_c  -> per-(b,c) sum / sumsq only ----------------
__global__ __launch_bounds__(256) void k_h2stats(const __half* __restrict__ h1,
    const float* __restrict__ wc1, const float* __restrict__ bc1,
    const float* __restrict__ wc2, const float* __restrict__ bc2,
    float* __restrict__ rs) {
  int blk = blockIdx.x; int net = blk >> 8, b = blk & 255;
  int t = threadIdx.x, tc = t >> 4, tp = t & 15;
  __shared__ __half2 WcTh[128][64];   // [cin][cout-pair]: pair = couts (2*co2, 2*co2+1)
  __shared__ float h1s[128][64];      // [cin][p-chunk]
  const float* wc = net ? wc2 : wc1;
  const float* bc = net ? bc2 : bc1;
  // transpose-stage Wc to fp16 pairs (2048 tasks, 8 iters x 256 threads)
  for (int it = 0; it < 8; ++it) {
    int task = it*256 + t;
    int co2 = task & 63;
    int cb  = (task >> 6) * 4;
    float4 a  = *(const float4*)(wc + (size_t)(2*co2)*128 + cb);
    float4 bv = *(const float4*)(wc + (size_t)(2*co2+1)*128 + cb);
    WcTh[cb+0][co2] = __floats2half2_rn(a.x, bv.x);
    WcTh[cb+1][co2] = __floats2half2_rn(a.y, bv.y);
    WcTh[cb+2][co2] = __floats2half2_rn(a.z, bv.z);
    WcTh[cb+3][co2] = __floats2half2_rn(a.w, bv.w);
  }
  float bias[8];
  #pragma unroll
  for (int i = 0; i < 8; ++i) bias[i] = bc[8*tc + i];
  float srow[8], ssrow[8];
  #pragma unroll
  for (int i = 0; i < 8; ++i) { srow[i] = 0.f; ssrow[i] = 0.f; }
  const __half* h1b = h1 + (size_t)(net*256 + b) * 131072;
  for (int pc = 0; pc < 16; ++pc) {
    __syncthreads();
    #pragma unroll
    for (int r = 0; r < 8; ++r) {
      int row = r*16 + tc;
      const __half2* src = (const __half2*)(h1b + (size_t)row*1024 + pc*64 + tp*4);
      float2 f0 = __half22float2(src[0]);
      float2 f1 = __half22float2(src[1]);
      *(float4*)&h1s[row][tp*4] = make_float4(f0.x, f0.y, f1.x, f1.y);
    }
    __syncthreads();
    float acc[8][4];
    #pragma unroll
    for (int i = 0; i < 8; ++i) { acc[i][0]=0.f; acc[i][1]=0.f; acc[i][2]=0.f; acc[i][3]=0.f; }
    #pragma unroll 2
    for (int cp = 0; cp < 128; ++cp) {
      float2 p0 = __half22float2(WcTh[cp][4*tc+0]);
      float2 p1 = __half22float2(WcTh[cp][4*tc+1]);
      float2 p2 = __half22float2(WcTh[cp][4*tc+2]);
      float2 p3 = __half22float2(WcTh[cp][4*tc+3]);
      float4 hv = *(const float4*)&h1s[cp][4*tp];
      float wv[8] = {p0.x,p0.y,p1.x,p1.y,p2.x,p2.y,p3.x,p3.y};
      float pv[4] = {hv.x,hv.y,hv.z,hv.w};
      #pragma unroll
      for (int i = 0; i < 8; ++i)
        #pragma unroll
        for (int j = 0; j < 4; ++j) acc[i][j] = __builtin_fmaf(wv[i], pv[j], acc[i][j]);
    }
    #pragma unroll
    for (int i = 0; i < 8; ++i) {
      float v0 = acc[i][0]+bias[i], v1 = acc[i][1]+bias[i], v2 = acc[i][2]+bias[i], v3 = acc[i][3]+bias[i];
      srow[i]  += v0+v1+v2+v3;
      ssrow[i] += v0*v0+v1*v1+v2*v2+v3*v3;
    }
  }
  float* rsb = rs + (size_t)(net*256 + b) * 256;
  #pragma unroll
  for (int i = 0; i < 8; ++i) {
    float s = srow[i], q = ssrow[i];
    #pragma unroll
    for (int m = 1; m < 16; m <<= 1) { s += __shfl_xor(s, m, 64); q += __shfl_xor(q, m, 64); }
    if (tp == 0) { rsb[2*(8*tc+i)] = s; rsb[2*(8*tc+i)+1] = q; }
  }
}

// ---------------- K5: BN2 channel params from rowstats ----------------
__global__ void k_bn2(const float* __restrict__ rs,
                      const float* __restrict__ g21, const float* __restrict__ g22,
                      float* __restrict__ bn2) {
  int t = threadIdx.x; int net = t >> 7, c = t & 127;
  float s = 0.f, q = 0.f;
  for (int b = 0; b < 256; ++b) {
    const float* p = rs + (size_t)(net*256 + b) * 256 + 2*c;
    s += p[0]; q += p[1];
  }
  const float inv = 1.f / (256.f * 1024.f);
  float mean = s * inv;
  float var = fmaxf(q*inv - mean*mean, 0.f);
  float gc = (net ? g22 : g21)[c];
  float aa = gc*gc / (var + EPSF);
  float sgn = (gc > 0.f) ? 1.f : ((gc < 0.f) ? -1.f : 0.f);
  float epsp = (aa > 0.f) ? (EPSF / aa) : 1.f;
  bn2[2*(net*128+c)]   = epsp;
  bn2[2*(net*128+c)+1] = sgn;
}

// ---------------- K4b: recompute h2, hf = relu(inorm(h2)) + h1, overwrite h1 in place ----------------
__global__ __launch_bounds__(256) void k_hf(__half* __restrict__ h1,
    const float* __restrict__ wc1, const float* __restrict__ bc1,
    const float* __restrict__ wc2, const float* __restrict__ bc2,
    const float* __restrict__ rs, const float* __restrict__ bn2) {
  int blk = blockIdx.x; int net = blk >> 8, b = blk & 255;
  int t = threadIdx.x, tc = t >> 4, tp = t & 15;
  __shared__ __half2 WcTh[128][64];
  __shared__ float h1s[128][64];
  const float* wc = net ? wc2 : wc1;
  const float* bc = net ? bc2 : bc1;
  for (int it = 0; it < 8; ++it) {
    int task = it*256 + t;
    int co2 = task & 63;
    int cb  = (task >> 6) * 4;
    float4 a  = *(const float4*)(wc + (size_t)(2*co2)*128 + cb);
    float4 bv = *(const float4*)(wc + (size_t)(2*co2+1)*128 + cb);
    WcTh[cb+0][co2] = __floats2half2_rn(a.x, bv.x);
    WcTh[cb+1][co2] = __floats2half2_rn(a.y, bv.y);
    WcTh[cb+2][co2] = __floats2half2_rn(a.z, bv.z);
    WcTh[cb+3][co2] = __floats2half2_rn(a.w, bv.w);
  }
  float bias[8], mu[8], al[8];
  #pragma unroll
  for (int i = 0; i < 8; ++i) {
    int c = 8*tc + i;
    bias[i] = bc[c];
    const float* p = rs + (size_t)(net*256 + b) * 256 + 2*c;
    float s = p[0], q = p[1];
    float m = s * (1.f/1024.f);
    float var = fmaxf(q * (1.f/1024.f) - m*m, 0.f);
    float ep = bn2[2*(net*128+c)], sg = bn2[2*(net*128+c)+1];
    mu[i] = m; al[i] = sg * rsqrtf(var + ep);
  }
  __half* h1b = h1 + (size_t)(net*256 + b) * 131072;
  for (int pc = 0; pc < 16; ++pc) {
    __syncthreads();
    #pragma unroll
    for (int r = 0; r < 8; ++r) {
      int row = r*16 + tc;
      const __half2* src = (const __half2*)(h1b + (size_t)row*1024 + pc*64 + tp*4);
      float2 f0 = __half22float2(src[0]);
      float2 f1 = __half22float2(src[1]);
      *(float4*)&h1s[row][tp*4] = make_float4(f0.x, f0.y, f1.x, f1.y);
    }
    __syncthreads();
    float acc[8][4];
    #pragma unroll
    for (int i = 0; i < 8; ++i) { acc[i][0]=0.f; acc[i][1]=0.f; acc[i][2]=0.f; acc[i][3]=0.f; }
    #pragma unroll 2
    for (int cp = 0; cp < 128; ++cp) {
      float2 p0 = __half22float2(WcTh[cp][4*tc+0]);
      float2 p1 = __half22float2(WcTh[cp][4*tc+1]);
      float2 p2 = __half22float2(WcTh[cp][4*tc+2]);
      float2 p3 = __half22float2(WcTh[cp][4*tc+3]);
      float4 hv = *(const float4*)&h1s[cp][4*tp];
      float wv[8] = {p0.x,p0.y,p1.x,p1.y,p2.x,p2.y,p3.x,p3.y};
      float pv[4] = {hv.x,hv.y,hv.z,hv.w};
      #pragma unroll
      for (int i = 0; i < 8; ++i)
        #pragma unroll
        for (int j = 0; j < 4; ++j) acc[i][j] = __builtin_fmaf(wv[i], pv[j], acc[i][j]);
    }
    #pragma unroll
    for (int i = 0; i < 8; ++i) {
      int row = 8*tc + i;
      float o[4];
      #pragma unroll
      for (int j = 0; j < 4; ++j) {
        float v = acc[i][j] + bias[i];
        o[j] = fmaxf((v - mu[i]) * al[i], 0.f) + h1s[row][4*tp + j];
      }
      __half2* dst = (__half2*)(h1b + (size_t)row*1024 + pc*64 + tp*4);
      dst[0] = __floats2half2_rn(o[0], o[1]);
      dst[1] = __floats2half2_rn(o[2], o[3]);
    }
  }
}

// ---------------- K6: f += hf @ wfc^T  (K-split over c, atomic) ----------------
__global__ __launch_bounds__(256) void k_fgemm(const __half* __restrict__ hf,
    const float* __restrict__ wfc1, const float* __restrict__ wfc2,
    float* __restrict__ f) {
  int bid = blockIdx.x;                 // 512 = 2 net x 2 btile x 128 c
  int net = bid >> 8;
  int bt  = (bid >> 7) & 1;
  int c   = bid & 127;
  int t = threadIdx.x, tm = t >> 4, tn = t & 15;
  __shared__ float As[32][192];   // col = b + 4*(b>>3) (pad-swizzle)
  __shared__ float Ws[32][192];   // col = o + 4*(o>>3)
  const float* wfc = net ? wfc2 : wfc1;
  int b0 = bt * 128;
  float acc[8][8];
  #pragma unroll
  for (int i = 0; i < 8; ++i)
    #pragma unroll
    for (int j = 0; j < 8; ++j) acc[i][j] = 0.f;
  size_t cbase = (size_t)c * 1024;
  for (int ks = 0; ks < 32; ++ks) {
    int k0 = ks * 32;
    __syncthreads();
    // stage A = hf (fp16 -> fp32)
    #pragma unroll
    for (int sl = 0; sl < 2; ++sl) {
      int b_i = (t >> 2) + 64*sl;
      int seg = t & 3;
      const __half* src = hf + (size_t)(net*256 + b0 + b_i) * 131072 + cbase + k0 + seg*8;
      float4 raw = *(const float4*)src;           // 8 halves
      const __half2* hp = (const __half2*)&raw;
      int colb = b_i + 4*(b_i >> 3);
      #pragma unroll
      for (int e = 0; e < 4; ++e) {
        float2 fv = __half22float2(hp[e]);
        As[seg*8 + 2*e][colb]     = fv.x;
        As[seg*8 + 2*e + 1][colb] = fv.y;
      }
    }
    // stage W
    #pragma unroll
    for (int r = 0; r < 4; ++r) {
      int o = (t >> 3) + 32*r;
      int kk = (t & 7) * 4;
      float4 v = *(const float4*)(wfc + (size_t)o * 131072 + cbase + k0 + kk);
      int colo = o + 4*(o >> 3);
      Ws[kk+0][colo] = v.x; Ws[kk+1][colo] = v.y; Ws[kk+2][colo] = v.z; Ws[kk+3][colo] = v.w;
    }
    __syncthreads();
    #pragma unroll 4
    for (int k = 0; k < 32; ++k) {
      float4 a0 = *(const float4*)&As[k][12*tm];
      float4 a1 = *(const float4*)&As[k][12*tm + 4];
      float4 w0 = *(const float4*)&Ws[k][12*tn];
      float4 w1 = *(const float4*)&Ws[k][12*tn + 4];
      float av[8] = {a0.x,a0.y,a0.z,a0.w,a1.x,a1.y,a1.z,a1.w};
      float wv[8] = {w0.x,w0.y,w0.z,w0.w,w1.x,w1.y,w1.z,w1.w};
      #pragma unroll
      for (int i = 0; i < 8; ++i)
        #pragma unroll
        for (int j = 0; j < 8; ++j) acc[i][j] = __builtin_fmaf(av[i], wv[j], acc[i][j]);
    }
  }
  #pragma unroll
  for (int i = 0; i < 8; ++i) {
    int bb = b0 + 8*tm + i;
    #pragma unroll
    for (int j = 0; j < 8; ++j)
      atomicAdd(f + (size_t)bb*256 + net*128 + 8*tn + j, acc[i][j]);
  }
}

// ---------------- tail: z1 = y @ w1^T + bh1 ----------------
__global__ __launch_bounds__(256) void k_t1(const float* __restrict__ f, const float* __restrict__ w1,
                                            const float* __restrict__ bh1, float* __restrict__ z1) {
  int b = blockIdx.x, t = threadIdx.x, wid = t >> 6, lane = t & 63;
  __shared__ float ys[256];
  ys[t] = f[b*256 + t];
  __syncthreads();
  for (int j = wid; j < 256; j += 4) {
    const float* wr = w1 + j*256;
    float a = ys[lane]*wr[lane] + ys[lane+64]*wr[lane+64] + ys[lane+128]*wr[lane+128] + ys[lane+192]*wr[lane+192];
    #pragma unroll
    for (int m = 1; m < 64; m <<= 1) a += __shfl_xor(a, m, 64);
    if (lane == 0) z1[b*256 + j] = a + bh1[j];
  }
}

// ---------------- tail: per-column batch stats -> scale/shift ----------------
__global__ void k_colstats(const float* __restrict__ z, const float* __restrict__ g,
                           const float* __restrict__ be, float* __restrict__ bp, int ncols) {
  int j = threadIdx.x;
  float s = 0.f, q = 0.f;
  for (int r = 0; r < 256; ++r) { float v = z[r*ncols + j]; s += v; q += v*v; }
  float mean = s * (1.f/256.f);
  float var = fmaxf(q * (1.f/256.f) - mean*mean, 0.f);
  float sc = g[j] * rsqrtf(var + EPSF);
  bp[2*j] = sc; bp[2*j+1] = be[j] - mean*sc;
}

// ---------------- tail: z2 = relu(bn(z1)) @ w2^T + bh2 ----------------
__global__ __launch_bounds__(256) void k_t3(const float* __restrict__ z1, const float* __restrict__ bp1,
                                            const float* __restrict__ w2, const float* __restrict__ bh2,
                                            float* __restrict__ z2) {
  int b = blockIdx.x, t = threadIdx.x, wid = t >> 6, lane = t & 63;
  __shared__ float ys[256];
  ys[t] = fmaxf(z1[b*256 + t]*bp1[2*t] + bp1[2*t+1], 0.f);
  __syncthreads();
  for (int j = wid; j < 128; j += 4) {
    const float* wr = w2 + j*256;
    float a = ys[lane]*wr[lane] + ys[lane+64]*wr[lane+64] + ys[lane+128]*wr[lane+128] + ys[lane+192]*wr[lane+192];
    #pragma unroll
    for (int m = 1; m < 64; m <<= 1) a += __shfl_xor(a, m, 64);
    if (lane == 0) z2[b*128 + j] = a + bh2[j];
  }
}

// ---------------- tail: y3 + symmetric 4x4 Jacobi eigensolver ----------------
__global__ __launch_bounds__(256) void k_t5(const float* __restrict__ z2, const float* __restrict__ bp2,
                                            const float* __restrict__ w3, const float* __restrict__ bh3,
                                            float* __restrict__ out) {
  __shared__ float w3s[2048];
  __shared__ float sc[128], sh[128], b3[16];
  int t = threadIdx.x;
  for (int i = t; i < 2048; i += 256) w3s[i] = w3[i];
  if (t < 128) { sc[t] = bp2[2*t]; sh[t] = bp2[2*t+1]; }
  if (t < 16) b3[t] = bh3[t];
  __syncthreads();
  int b = t;
  float r[128];
  #pragma unroll
  for (int i = 0; i < 128; i += 4) {
    float4 v = *(const float4*)(z2 + b*128 + i);
    r[i]   = fmaxf(v.x*sc[i]   + sh[i],   0.f);
    r[i+1] = fmaxf(v.y*sc[i+1] + sh[i+1], 0.f);
    r[i+2] = fmaxf(v.z*sc[i+2] + sh[i+2], 0.f);
    r[i+3] = fmaxf(v.w*sc[i+3] + sh[i+3], 0.f);
  }
  float y3[16];
  #pragma unroll
  for (int j = 0; j < 16; ++j) {
    float a = b3[j];
    #pragma unroll
    for (int i = 0; i < 128; ++i) a += r[i]*w3s[j*128 + i];
    y3[j] = a;
  }
  double A[4][4], V[4][4];
  #pragma unroll
  for (int i2 = 0; i2 < 4; ++i2)
    #pragma unroll
    for (int j2 = 0; j2 < 4; ++j2) {
      A[i2][j2] = 0.5 * ((double)y3[4*i2 + j2] + (double)y3[4*j2 + i2]);
      V[i2][j2] = (i2 == j2) ? 1.0 : 0.0;
    }
  for (int sweep = 0; sweep < 12; ++sweep) {
    #pragma unroll
    for (int pi = 0; pi < 6; ++pi) {
      const int PP[6] = {0,0,0,1,1,2};
      const int QQ[6] = {1,2,3,2,3,3};
      int p = PP[pi], q = QQ[pi];
      double apq = A[p][q];
      if (fabs(apq) > 1e-300) {
        double tau = (A[q][q] - A[p][p]) / (2.0 * apq);
        double tt = (tau >= 0.0 ? 1.0 : -1.0) / (fabs(tau) + sqrt(1.0 + tau*tau));
        double cc = 1.0 / sqrt(1.0 + tt*tt);
        double sn = tt * cc;
        #pragma unroll
        for (int k2 = 0; k2 < 4; ++k2) {
          double akp = A[k2][p], akq = A[k2][q];
          A[k2][p] = cc*akp - sn*akq;
          A[k2][q] = sn*akp + cc*akq;
        }
        #pragma unroll
        for (int k2 = 0; k2 < 4; ++k2) {
          double apk = A[p][k2], aqk = A[q][k2];
          A[p][k2] = cc*apk - sn*aqk;
          A[q][k2] = sn*apk + cc*aqk;
        }
        #pragma unroll
        for (int k2 = 0; k2 < 4; ++k2) {
          double vkp = V[k2][p], vkq = V[k2][q];
          V[k2][p] = cc*vkp - sn*vkq;
          V[k2][q] = sn*vkp + cc*vkq;
        }
      }
    }
  }
  int imin = 0; double mv = A[0][0];
  if (A[1][1] < mv) { mv = A[1][1]; imin = 1; }
  if (A[2][2] < mv) { mv = A[2][2]; imin = 2; }
  if (A[3][3] < mv) { mv = A[3][3]; imin = 3; }
  double q0 = (imin==0)?V[0][0]:(imin==1)?V[0][1]:(imin==2)?V[0][2]:V[0][3];
  double q1 = (imin==0)?V[1][0]:(imin==1)?V[1][1]:(imin==2)?V[1][2]:V[1][3];
  double q2 = (imin==0)?V[2][0]:(imin==1)?V[2][1]:(imin==2)?V[2][2]:V[2][3];
  double q3 = (imin==0)?V[3][0]:(imin==1)?V[3][1]:(imin==2)?V[3][2]:V[3][3];
  if (q0 < 0.0) { q0 = -q0; q1 = -q1; q2 = -q2; q3 = -q3; }
  out[4*b+0] = (float)q0; out[4*b+1] = (float)q1; out[4*b+2] = (float)q2; out[4*b+3] = (float)q3;
}

extern "C" void kernel_launch(void* const* d_in, const int* in_sizes, int n_in,
                              void* d_out, int out_size, void* d_ws, size_t ws_size,
                              hipStream_t stream) {
  (void)in_sizes; (void)n_in; (void)out_size; (void)ws_size;
  const float* x    = (const float*)d_in[0];
  const float* win1 = (const float*)d_in[1];
  const float* bin1 = (const float*)d_in[2];
  const float* g11  = (const float*)d_in[3];
  const float* wc1  = (const float*)d_in[5];
  const float* bc1  = (const float*)d_in[6];
  const float* g21  = (const float*)d_in[7];
  const float* wfc1 = (const float*)d_in[9];
  const float* bfc1 = (const float*)d_in[10];
  const float* win2 = (const float*)d_in[11];
  const float* bin2 = (const float*)d_in[12];
  const float* g12  = (const float*)d_in[13];
  const float* wc2  = (const float*)d_in[15];
  const float* bc2  = (const float*)d_in[16];
  const float* g22  = (const float*)d_in[17];
  const float* wfc2 = (const float*)d_in[19];
  const float* bfc2 = (const float*)d_in[20];
  const float* w1   = (const float*)d_in[21];
  const float* bh1  = (const float*)d_in[22];
  const float* gb1  = (const float*)d_in[23];
  const float* beb1 = (const float*)d_in[24];
  const float* w2   = (const float*)d_in[25];
  const float* bh2  = (const float*)d_in[26];
  const float* gb2  = (const float*)d_in[27];
  const float* beb2 = (const float*)d_in[28];
  const float* w3   = (const float*)d_in[29];
  const float* bh3  = (const float*)d_in[30];

  char* ws = (char*)d_ws;
  __half* h1  = (__half*)(ws + 0);                  // [2][256][128][1024] fp16 = 134,217,728 B
  float* rsB  = (float*)(ws + 134217728ULL);        // [2][256][128][2]       =     524,288 B
  float* xmom = (float*)(ws + 134742016ULL);        // [2][16]
  float* bn1a = (float*)(ws + 134742272ULL);        // [2][128][2]
  float* bn2a = (float*)(ws + 134744320ULL);        // [2][128][2]
  float* f    = (float*)(ws + 134746368ULL);        // [256][256]
  float* z1   = (float*)(ws + 135008512ULL);        // [256][256]
  float* bp1  = (float*)(ws + 135270656ULL);        // [256][2]
  float* z2   = (float*)(ws + 135272704ULL);        // [256][128]
  float* bp2  = (float*)(ws + 135403776ULL);        // [128][2]

  hipLaunchKernelGGL(k_init,     dim3(256), dim3(256), 0, stream, f, bfc1, bfc2, xmom);
  hipLaunchKernelGGL(k_xmom,     dim3(256), dim3(256), 0, stream, x, xmom);
  hipLaunchKernelGGL(k_bn1,      dim3(1),   dim3(256), 0, stream, xmom, win1, bin1, g11, win2, bin2, g12, bn1a);
  hipLaunchKernelGGL(k_h1,       dim3(512), dim3(256), 0, stream, x, win1, bin1, win2, bin2, bn1a, h1);
  hipLaunchKernelGGL(k_h2stats,  dim3(512), dim3(256), 0, stream, h1, wc1, bc1, wc2, bc2, rsB);
  hipLaunchKernelGGL(k_bn2,      dim3(1),   dim3(256), 0, stream, rsB, g21, g22, bn2a);
  hipLaunchKernelGGL(k_hf,       dim3(512), dim3(256), 0, stream, h1, wc1, bc1, wc2, bc2, rsB, bn2a);
  hipLaunchKernelGGL(k_fgemm,    dim3(512), dim3(256), 0, stream, h1, wfc1, wfc2, f);
  hipLaunchKernelGGL(k_t1,       dim3(256), dim3(256), 0, stream, f, w1, bh1, z1);
  hipLaunchKernelGGL(k_colstats, dim3(1),   dim3(256), 0, stream, z1, gb1, beb1, bp1, 256);
  hipLaunchKernelGGL(k_t3,       dim3(256), dim3(256), 0, stream, z1, bp1, w2, bh2, z2);
  hipLaunchKernelGGL(k_colstats, dim3(1),   dim3(128), 0, stream, z2, gb2, beb2, bp2, 128);
  hipLaunchKernelGGL(k_t5,       dim3(1),   dim3(256), 0, stream, z2, bp2, w3, bh3, (float*)d_out);
}

// Round 3
// 688.241 us; speedup vs baseline: 2.3910x; 2.3910x over previous
//
#include <hip/hip_runtime.h>
#include <hip/hip_bf16.h>
#include <hip/hip_fp16.h>
#include <math.h>

#define EPSF 1e-5f

typedef _Float16 f16;
typedef __attribute__((ext_vector_type(8))) _Float16 f16x8;
typedef __attribute__((ext_vector_type(4))) float f32x4;
#define MFMA16(a, b, c) __builtin_amdgcn_mfma_f32_16x16x32_f16(a, b, c, 0, 0, 0)

// ---------------- init: f = bias rows, zero xmom + rs ----------------
__global__ void k_init(float* __restrict__ f, const float* __restrict__ bfc1,
                       const float* __restrict__ bfc2, float* __restrict__ xmom,
                       float* __restrict__ rs) {
  int t = blockIdx.x * 256 + threadIdx.x;  // 65536 total
  int col = t & 255;
  f[t] = (col < 128) ? bfc1[col] : bfc2[col & 127];
  rs[t] = 0.f; rs[t + 65536] = 0.f;
  if (t < 32) xmom[t] = 0.f;
}

// ---------------- K1: second moments of x per net ----------------
__global__ __launch_bounds__(256) void k_xmom(const float* __restrict__ x, float* __restrict__ xmom) {
  int b = blockIdx.x, t = threadIdx.x;
  const float* xr = x + (size_t)b * 6144;
  for (int net = 0; net < 2; ++net) {
    float a[9] = {0,0,0,0,0,0,0,0,0};
    const float* xn = xr + net * 3072;
    for (int p = t; p < 1024; p += 256) {
      float x0 = xn[3*p], x1 = xn[3*p+1], x2 = xn[3*p+2];
      a[0]+=x0; a[1]+=x1; a[2]+=x2;
      a[3]+=x0*x0; a[4]+=x0*x1; a[5]+=x0*x2;
      a[6]+=x1*x1; a[7]+=x1*x2; a[8]+=x2*x2;
    }
    #pragma unroll
    for (int i = 0; i < 9; ++i) {
      float v = a[i];
      #pragma unroll
      for (int m = 1; m < 64; m <<= 1) v += __shfl_xor(v, m, 64);
      if ((t & 63) == 0) atomicAdd(&xmom[net*16 + i], v);
    }
  }
}

// ---------------- K2: BN1 channel params (eps', sign) ----------------
__global__ void k_bn1(const float* __restrict__ xmom,
                      const float* __restrict__ win1, const float* __restrict__ bin1, const float* __restrict__ g11,
                      const float* __restrict__ win2, const float* __restrict__ bin2, const float* __restrict__ g12,
                      float* __restrict__ bn1) {
  int t = threadIdx.x; int net = t >> 7, c = t & 127;
  const float* win = net ? win2 : win1;
  const float* bin = net ? bin2 : bin1;
  const float* g   = net ? g12  : g11;
  const float* m = xmom + net * 16;
  const float inv = 1.f / (256.f * 1024.f);
  float w0 = win[3*c], w1 = win[3*c+1], w2 = win[3*c+2], bi = bin[c];
  float s0 = m[0]*inv, s1 = m[1]*inv, s2 = m[2]*inv;
  float lin = w0*s0 + w1*s1 + w2*s2;
  float mean = lin + bi;
  float e2 = (w0*w0*m[3] + 2.f*w0*w1*m[4] + 2.f*w0*w2*m[5] + w1*w1*m[6] + 2.f*w1*w2*m[7] + w2*w2*m[8]) * inv
             + 2.f*bi*lin + bi*bi;
  float var = fmaxf(e2 - mean*mean, 0.f);
  float gc = g[c];
  float aa = gc*gc / (var + EPSF);
  float sgn = (gc > 0.f) ? 1.f : ((gc < 0.f) ? -1.f : 0.f);
  float epsp = (aa > 0.f) ? (EPSF / aa) : 1.f;
  bn1[2*(net*128+c)]   = epsp;
  bn1[2*(net*128+c)+1] = sgn;
}

// ---------------- K3: h1 = relu(inorm(bn1(W_in x))) -> fp16 [cin][p] ----------------
__global__ __launch_bounds__(256) void k_h1(const float* __restrict__ x,
    const float* __restrict__ win1, const float* __restrict__ bin1,
    const float* __restrict__ win2, const float* __restrict__ bin2,
    const float* __restrict__ bn1, __half* __restrict__ h1) {
  int blk = blockIdx.x; int net = blk >> 8, b = blk & 255;
  int t = threadIdx.x, wid = t >> 6, lane = t & 63;
  __shared__ float xs[3072];
  const float4* xr = (const float4*)(x + (size_t)b*6144 + net*3072);
  float4* xsv = (float4*)xs;
  for (int i = t; i < 768; i += 256) xsv[i] = xr[i];
  __syncthreads();
  const float* win = net ? win2 : win1;
  const float* bin = net ? bin2 : bin1;
  __half* out = h1 + (size_t)(net*256 + b) * 131072;
  for (int c = wid; c < 128; c += 4) {
    float w0 = win[3*c], w1 = win[3*c+1], w2 = win[3*c+2], bi = bin[c];
    float h[16];
    float s = 0.f, ss = 0.f;
    #pragma unroll
    for (int j = 0; j < 8; ++j) {
      int base = 6*lane + 384*j;
      float2 d0 = *(const float2*)&xs[base];
      float2 d1 = *(const float2*)&xs[base+2];
      float2 d2 = *(const float2*)&xs[base+4];
      float v0 = w0*d0.x + w1*d0.y + w2*d1.x + bi;
      float v1 = w0*d1.y + w1*d2.x + w2*d2.y + bi;
      h[2*j] = v0; h[2*j+1] = v1;
      s += v0 + v1; ss += v0*v0 + v1*v1;
    }
    #pragma unroll
    for (int m = 1; m < 64; m <<= 1) { s += __shfl_xor(s, m, 64); ss += __shfl_xor(ss, m, 64); }
    float mean = s * (1.f/1024.f);
    float var  = fmaxf(ss * (1.f/1024.f) - mean*mean, 0.f);
    float epsp = bn1[2*(net*128+c)], sgn = bn1[2*(net*128+c)+1];
    float isd = sgn * rsqrtf(var + epsp);
    #pragma unroll
    for (int j = 0; j < 8; ++j) {
      float r0 = fmaxf((h[2*j]   - mean)*isd, 0.f);
      float r1 = fmaxf((h[2*j+1] - mean)*isd, 0.f);
      *(__half2*)(out + (size_t)c*1024 + 2*lane + 128*j) = __floats2half2_rn(r0, r1);
    }
  }
}

// ======= shared MFMA helpers for the 128x128 channel GEMM =======
// Wc LDS layout: byte(cout, cin8) = cout*256 + ((cin8 ^ (cout&7))<<4)   [32 KB]
// h1-tile (B) LDS layout (transposed): byte(sl, p) = sl*2048 + ((p ^ (sl&7))<<4)  [32 KB, 128p-chunk]

__device__ __forceinline__ void stage_wc(char* sW, const float* wc, int t) {
  int cin8 = t & 15, cout0 = t >> 4;
  #pragma unroll
  for (int it = 0; it < 8; ++it) {
    int cout = cout0 + 16*it;
    const float* src = wc + cout*128 + cin8*8;
    float4 v0 = *(const float4*)src;
    float4 v1 = *(const float4*)(src + 4);
    f16x8 h = {(f16)v0.x,(f16)v0.y,(f16)v0.z,(f16)v0.w,(f16)v1.x,(f16)v1.y,(f16)v1.z,(f16)v1.w};
    *(f16x8*)(sW + cout*256 + ((cin8 ^ (cout & 7)) << 4)) = h;
  }
}

__device__ __forceinline__ void stage_btile(char* sB, const __half* h1b, int pch, int t) {
  int c = t & 63, pg0 = t >> 6;
  const __half* r0 = h1b + (size_t)(2*c)*1024 + pch*128;
  const __half* r1 = r0 + 1024;
  int sl = c >> 2;
  int ebyte = (c & 3) * 4;
  #pragma unroll
  for (int it = 0; it < 4; ++it) {
    int pg = pg0 + 4*it;
    uint4 ua = *(const uint4*)(r0 + pg*8);
    uint4 ub = *(const uint4*)(r1 + pg*8);
    unsigned A[4] = {ua.x, ua.y, ua.z, ua.w};
    unsigned B[4] = {ub.x, ub.y, ub.z, ub.w};
    #pragma unroll
    for (int j = 0; j < 8; ++j) {
      int p = pg*8 + j;
      unsigned lo = (A[j >> 1] >> ((j & 1) * 16)) & 0xffffu;
      unsigned hi = (B[j >> 1] >> ((j & 1) * 16)) & 0xffffu;
      *(unsigned*)(sB + sl*2048 + ((p ^ (sl & 7)) << 4) + ebyte) = lo | (hi << 16);
    }
  }
}

// ---------------- K4a: h2 row stats via MFMA (sum/sumsq per (b,cout)) ----------------
__global__ __launch_bounds__(256) void k_h2stats(const __half* __restrict__ h1,
    const float* __restrict__ wc1, const float* __restrict__ bc1,
    const float* __restrict__ wc2, const float* __restrict__ bc2,
    float* __restrict__ rs) {
  int blk = blockIdx.x; int net = blk >> 8, b = blk & 255;
  int t = threadIdx.x, wv = t >> 6, l = t & 63;
  __shared__ __align__(16) char sW[32768];
  __shared__ __align__(16) char sB[32768];
  const float* wc = net ? wc2 : wc1;
  const float* bc = net ? bc2 : bc1;
  stage_wc(sW, wc, t);
  __syncthreads();
  f16x8 afr[2][4];
  #pragma unroll
  for (int rt = 0; rt < 2; ++rt)
    #pragma unroll
    for (int kk = 0; kk < 4; ++kk) {
      int row = wv*32 + rt*16 + (l & 15);
      int cin8 = kk*4 + (l >> 4);
      afr[rt][kk] = *(const f16x8*)(sW + row*256 + ((cin8 ^ (row & 7)) << 4));
    }
  const __half* h1b = h1 + (size_t)(net*256 + b) * 131072;
  float sacc[2][4], qacc[2][4];
  #pragma unroll
  for (int rt = 0; rt < 2; ++rt)
    #pragma unroll
    for (int r = 0; r < 4; ++r) { sacc[rt][r] = 0.f; qacc[rt][r] = 0.f; }
  for (int pch = 0; pch < 8; ++pch) {
    __syncthreads();
    stage_btile(sB, h1b, pch, t);
    __syncthreads();
    #pragma unroll 2
    for (int pt = 0; pt < 8; ++pt) {
      f16x8 bf[4];
      #pragma unroll
      for (int kk = 0; kk < 4; ++kk) {
        int sl = kk*4 + (l >> 4);
        int p = pt*16 + (l & 15);
        bf[kk] = *(const f16x8*)(sB + sl*2048 + ((p ^ (sl & 7)) << 4));
      }
      f32x4 a0 = {0.f,0.f,0.f,0.f}, a1 = {0.f,0.f,0.f,0.f};
      #pragma unroll
      for (int kk = 0; kk < 4; ++kk) a0 = MFMA16(afr[0][kk], bf[kk], a0);
      #pragma unroll
      for (int kk = 0; kk < 4; ++kk) a1 = MFMA16(afr[1][kk], bf[kk], a1);
      #pragma unroll
      for (int r = 0; r < 4; ++r) {
        sacc[0][r] += a0[r]; qacc[0][r] += a0[r]*a0[r];
        sacc[1][r] += a1[r]; qacc[1][r] += a1[r]*a1[r];
      }
    }
  }
  #pragma unroll
  for (int rt = 0; rt < 2; ++rt)
    #pragma unroll
    for (int r = 0; r < 4; ++r) {
      float s = sacc[rt][r], q = qacc[rt][r];
      #pragma unroll
      for (int m = 1; m < 16; m <<= 1) { s += __shfl_xor(s, m, 64); q += __shfl_xor(q, m, 64); }
      if ((l & 15) == 0) {
        int row = wv*32 + rt*16 + ((l >> 4) << 2) + r;
        float bi = bc[row];
        float s2 = s + 1024.f*bi;
        float q2 = q + 2.f*bi*s + 1024.f*bi*bi;
        float* dst = rs + (size_t)(net*256 + b) * 256 + 2*row;
        atomicAdd(dst, s2);
        atomicAdd(dst + 1, q2);
      }
    }
}

// ---------------- K5: BN2 channel params from rowstats (parallel) ----------------
__global__ void k_bn2(const float* __restrict__ rs,
                      const float* __restrict__ g21, const float* __restrict__ g22,
                      float* __restrict__ bn2) {
  int blk = blockIdx.x;  // 256: net*128+c
  int net = blk >> 7, c = blk & 127;
  int t = threadIdx.x;   // b
  const float* p = rs + (size_t)(net*256 + t) * 256 + 2*c;
  float s = p[0], q = p[1];
  #pragma unroll
  for (int m = 1; m < 64; m <<= 1) { s += __shfl_xor(s, m, 64); q += __shfl_xor(q, m, 64); }
  __shared__ float ss[4], qq[4];
  if ((t & 63) == 0) { ss[t >> 6] = s; qq[t >> 6] = q; }
  __syncthreads();
  if (t == 0) {
    s = ss[0] + ss[1] + ss[2] + ss[3];
    q = qq[0] + qq[1] + qq[2] + qq[3];
    const float inv = 1.f / (256.f * 1024.f);
    float mean = s * inv;
    float var = fmaxf(q*inv - mean*mean, 0.f);
    float gc = (net ? g22 : g21)[c];
    float aa = gc*gc / (var + EPSF);
    float sgn = (gc > 0.f) ? 1.f : ((gc < 0.f) ? -1.f : 0.f);
    float epsp = (aa > 0.f) ? (EPSF / aa) : 1.f;
    bn2[2*(net*128+c)]   = epsp;
    bn2[2*(net*128+c)+1] = sgn;
  }
}

// ---------------- K4b: recompute h2 via MFMA, hf = relu(inorm(h2)) + h1 in place ----------------
__global__ __launch_bounds__(256) void k_hf(__half* __restrict__ h1,
    const float* __restrict__ wc1, const float* __restrict__ bc1,
    const float* __restrict__ wc2, const float* __restrict__ bc2,
    const float* __restrict__ rs, const float* __restrict__ bn2) {
  int blk = blockIdx.x; int net = blk >> 8, b = blk & 255;
  int t = threadIdx.x, wv = t >> 6, l = t & 63;
  __shared__ __align__(16) char sW[32768];
  __shared__ __align__(16) char sB[32768];
  const float* wc = net ? wc2 : wc1;
  const float* bc = net ? bc2 : bc1;
  stage_wc(sW, wc, t);
  __syncthreads();
  f16x8 afr[2][4];
  #pragma unroll
  for (int rt = 0; rt < 2; ++rt)
    #pragma unroll
    for (int kk = 0; kk < 4; ++kk) {
      int row = wv*32 + rt*16 + (l & 15);
      int cin8 = kk*4 + (l >> 4);
      afr[rt][kk] = *(const f16x8*)(sW + row*256 + ((cin8 ^ (row & 7)) << 4));
    }
  float mup[2][4], al[2][4];
  #pragma unroll
  for (int rt = 0; rt < 2; ++rt)
    #pragma unroll
    for (int r = 0; r < 4; ++r) {
      int row = wv*32 + rt*16 + ((l >> 4) << 2) + r;
      const float* pp = rs + (size_t)(net*256 + b) * 256 + 2*row;
      float sv = pp[0], qv = pp[1];
      float m = sv * (1.f/1024.f);
      float var = fmaxf(qv * (1.f/1024.f) - m*m, 0.f);
      float ep = bn2[2*(net*128+row)], sg = bn2[2*(net*128+row)+1];
      al[rt][r] = sg * rsqrtf(var + ep);
      mup[rt][r] = m - bc[row];
    }
  __half* h1b = h1 + (size_t)(net*256 + b) * 131072;
  for (int pch = 0; pch < 8; ++pch) {
    __syncthreads();
    stage_btile(sB, h1b, pch, t);
    __syncthreads();
    #pragma unroll 2
    for (int pt = 0; pt < 8; ++pt) {
      f16x8 bf[4];
      #pragma unroll
      for (int kk = 0; kk < 4; ++kk) {
        int sl = kk*4 + (l >> 4);
        int p = pt*16 + (l & 15);
        bf[kk] = *(const f16x8*)(sB + sl*2048 + ((p ^ (sl & 7)) << 4));
      }
      f32x4 a0 = {0.f,0.f,0.f,0.f}, a1 = {0.f,0.f,0.f,0.f};
      #pragma unroll
      for (int kk = 0; kk < 4; ++kk) a0 = MFMA16(afr[0][kk], bf[kk], a0);
      #pragma unroll
      for (int kk = 0; kk < 4; ++kk) a1 = MFMA16(afr[1][kk], bf[kk], a1);
      int prel = pt*16 + (l & 15);
      #pragma unroll
      for (int rt = 0; rt < 2; ++rt) {
        f32x4 av = rt ? a1 : a0;
        #pragma unroll
        for (int r = 0; r < 4; ++r) {
          int row = wv*32 + rt*16 + ((l >> 4) << 2) + r;
          int sl2 = row >> 3, e2 = row & 7;
          float resid = __half2float(*(const __half*)(sB + sl2*2048 + ((prel ^ (sl2 & 7)) << 4) + e2*2));
          float v = fmaxf((av[r] - mup[rt][r]) * al[rt][r], 0.f) + resid;
          h1b[(size_t)row*1024 + pch*128 + prel] = __float2half(v);
        }
      }
    }
  }
}

// ---------------- K6: f += hf @ wfc^T via MFMA (K-split, atomic) ----------------
__global__ __launch_bounds__(256) void k_fgemm(const __half* __restrict__ hf,
    const float* __restrict__ wfc1, const float* __restrict__ wfc2,
    float* __restrict__ f) {
  int bid = blockIdx.x;                 // 512 = 2 net x 4 bt x 64 ks
  int net = bid >> 8;
  int bt  = (bid >> 6) & 3;
  int ks  = bid & 63;
  int t = threadIdx.x, wv = t >> 6, l = t & 63;
  __shared__ __align__(16) char sA[4096];   // 64 b x 32 k fp16, swizzled
  __shared__ __align__(16) char sW[8192];   // 128 o x 32 k fp16, swizzled
  const float* wfc = net ? wfc2 : wfc1;
  int b0 = bt * 64;
  size_t kbase = (size_t)ks * 2048;
  f32x4 acc[8];
  #pragma unroll
  for (int ot = 0; ot < 8; ++ot) acc[ot] = (f32x4){0.f,0.f,0.f,0.f};
  const __half* hfb = hf + (size_t)(net*256 + b0) * 131072 + kbase;
  for (int step = 0; step < 64; ++step) {
    __syncthreads();
    {
      int bb = t >> 2, k8 = t & 3;
      uint4 v = *(const uint4*)(hfb + (size_t)bb * 131072 + step*32 + k8*8);
      *(uint4*)(sA + bb*64 + ((k8 ^ ((bb >> 1) & 3)) << 4)) = v;
    }
    #pragma unroll
    for (int i = 0; i < 2; ++i) {
      int task = t + 256*i;
      int o = task >> 2, k8 = task & 3;
      const float* src = wfc + (size_t)o * 131072 + kbase + step*32 + k8*8;
      float4 v0 = *(const float4*)src;
      float4 v1 = *(const float4*)(src + 4);
      f16x8 h = {(f16)v0.x,(f16)v0.y,(f16)v0.z,(f16)v0.w,(f16)v1.x,(f16)v1.y,(f16)v1.z,(f16)v1.w};
      *(f16x8*)(sW + o*64 + ((k8 ^ ((o >> 1) & 3)) << 4)) = h;
    }
    __syncthreads();
    int bb = wv*16 + (l & 15), k8 = l >> 4;
    f16x8 a = *(const f16x8*)(sA + bb*64 + ((k8 ^ ((bb >> 1) & 3)) << 4));
    #pragma unroll
    for (int ot = 0; ot < 8; ++ot) {
      int o = ot*16 + (l & 15);
      f16x8 bfr = *(const f16x8*)(sW + o*64 + ((k8 ^ ((o >> 1) & 3)) << 4));
      acc[ot] = MFMA16(a, bfr, acc[ot]);
    }
  }
  #pragma unroll
  for (int ot = 0; ot < 8; ++ot) {
    int col = net*128 + ot*16 + (l & 15);
    #pragma unroll
    for (int r = 0; r < 4; ++r) {
      int row = b0 + wv*16 + ((l >> 4) << 2) + r;
      atomicAdd(&f[(size_t)row*256 + col], acc[ot][r]);
    }
  }
}

// ---------------- tail: z1 = y @ w1^T + bh1 ----------------
__global__ __launch_bounds__(256) void k_t1(const float* __restrict__ f, const float* __restrict__ w1,
                                            const float* __restrict__ bh1, float* __restrict__ z1) {
  int b = blockIdx.x, t = threadIdx.x, wid = t >> 6, lane = t & 63;
  __shared__ float ys[256];
  ys[t] = f[b*256 + t];
  __syncthreads();
  for (int j = wid; j < 256; j += 4) {
    const float* wr = w1 + j*256;
    float a = ys[lane]*wr[lane] + ys[lane+64]*wr[lane+64] + ys[lane+128]*wr[lane+128] + ys[lane+192]*wr[lane+192];
    #pragma unroll
    for (int m = 1; m < 64; m <<= 1) a += __shfl_xor(a, m, 64);
    if (lane == 0) z1[b*256 + j] = a + bh1[j];
  }
}

// ---------------- tail: per-column batch stats (parallel) ----------------
__global__ void k_colstats(const float* __restrict__ z, const float* __restrict__ g,
                           const float* __restrict__ be, float* __restrict__ bp, int ncols) {
  int j = blockIdx.x, t = threadIdx.x;
  float v = z[(size_t)t * ncols + j];
  float s = v, q = v*v;
  #pragma unroll
  for (int m = 1; m < 64; m <<= 1) { s += __shfl_xor(s, m, 64); q += __shfl_xor(q, m, 64); }
  __shared__ float ss[4], qq[4];
  if ((t & 63) == 0) { ss[t >> 6] = s; qq[t >> 6] = q; }
  __syncthreads();
  if (t == 0) {
    s = ss[0] + ss[1] + ss[2] + ss[3];
    q = qq[0] + qq[1] + qq[2] + qq[3];
    float mean = s * (1.f/256.f);
    float var = fmaxf(q * (1.f/256.f) - mean*mean, 0.f);
    float sc = g[j] * rsqrtf(var + EPSF);
    bp[2*j] = sc; bp[2*j+1] = be[j] - mean*sc;
  }
}

// ---------------- tail: z2 = relu(bn(z1)) @ w2^T + bh2 ----------------
__global__ __launch_bounds__(256) void k_t3(const float* __restrict__ z1, const float* __restrict__ bp1,
                                            const float* __restrict__ w2, const float* __restrict__ bh2,
                                            float* __restrict__ z2) {
  int b = blockIdx.x, t = threadIdx.x, wid = t >> 6, lane = t & 63;
  __shared__ float ys[256];
  ys[t] = fmaxf(z1[b*256 + t]*bp1[2*t] + bp1[2*t+1], 0.f);
  __syncthreads();
  for (int j = wid; j < 128; j += 4) {
    const float* wr = w2 + j*256;
    float a = ys[lane]*wr[lane] + ys[lane+64]*wr[lane+64] + ys[lane+128]*wr[lane+128] + ys[lane+192]*wr[lane+192];
    #pragma unroll
    for (int m = 1; m < 64; m <<= 1) a += __shfl_xor(a, m, 64);
    if (lane == 0) z2[b*128 + j] = a + bh2[j];
  }
}

// ---------------- tail: y3 + symmetric 4x4 Jacobi eigensolver ----------------
__global__ __launch_bounds__(256) void k_t5(const float* __restrict__ z2, const float* __restrict__ bp2,
                                            const float* __restrict__ w3, const float* __restrict__ bh3,
                                            float* __restrict__ out) {
  __shared__ float w3s[2048];
  __shared__ float sc[128], sh[128], b3[16];
  int t = threadIdx.x;
  for (int i = t; i < 2048; i += 256) w3s[i] = w3[i];
  if (t < 128) { sc[t] = bp2[2*t]; sh[t] = bp2[2*t+1]; }
  if (t < 16) b3[t] = bh3[t];
  __syncthreads();
  int b = t;
  float r[128];
  #pragma unroll
  for (int i = 0; i < 128; i += 4) {
    float4 v = *(const float4*)(z2 + b*128 + i);
    r[i]   = fmaxf(v.x*sc[i]   + sh[i],   0.f);
    r[i+1] = fmaxf(v.y*sc[i+1] + sh[i+1], 0.f);
    r[i+2] = fmaxf(v.z*sc[i+2] + sh[i+2], 0.f);
    r[i+3] = fmaxf(v.w*sc[i+3] + sh[i+3], 0.f);
  }
  float y3[16];
  #pragma unroll
  for (int j = 0; j < 16; ++j) {
    float a = b3[j];
    #pragma unroll
    for (int i = 0; i < 128; ++i) a += r[i]*w3s[j*128 + i];
    y3[j] = a;
  }
  double A[4][4], V[4][4];
  #pragma unroll
  for (int i2 = 0; i2 < 4; ++i2)
    #pragma unroll
    for (int j2 = 0; j2 < 4; ++j2) {
      A[i2][j2] = 0.5 * ((double)y3[4*i2 + j2] + (double)y3[4*j2 + i2]);
      V[i2][j2] = (i2 == j2) ? 1.0 : 0.0;
    }
  for (int sweep = 0; sweep < 12; ++sweep) {
    #pragma unroll
    for (int pi = 0; pi < 6; ++pi) {
      const int PP[6] = {0,0,0,1,1,2};
      const int QQ[6] = {1,2,3,2,3,3};
      int p = PP[pi], q = QQ[pi];
      double apq = A[p][q];
      if (fabs(apq) > 1e-300) {
        double tau = (A[q][q] - A[p][p]) / (2.0 * apq);
        double tt = (tau >= 0.0 ? 1.0 : -1.0) / (fabs(tau) + sqrt(1.0 + tau*tau));
        double cc = 1.0 / sqrt(1.0 + tt*tt);
        double sn = tt * cc;
        #pragma unroll
        for (int k2 = 0; k2 < 4; ++k2) {
          double akp = A[k2][p], akq = A[k2][q];
          A[k2][p] = cc*akp - sn*akq;
          A[k2][q] = sn*akp + cc*akq;
        }
        #pragma unroll
        for (int k2 = 0; k2 < 4; ++k2) {
          double apk = A[p][k2], aqk = A[q][k2];
          A[p][k2] = cc*apk - sn*aqk;
          A[q][k2] = sn*apk + cc*aqk;
        }
        #pragma unroll
        for (int k2 = 0; k2 < 4; ++k2) {
          double vkp = V[k2][p], vkq = V[k2][q];
          V[k2][p] = cc*vkp - sn*vkq;
          V[k2][q] = sn*vkp + cc*vkq;
        }
      }
    }
  }
  int imin = 0; double mv = A[0][0];
  if (A[1][1] < mv) { mv = A[1][1]; imin = 1; }
  if (A[2][2] < mv) { mv = A[2][2]; imin = 2; }
  if (A[3][3] < mv) { mv = A[3][3]; imin = 3; }
  double q0 = (imin==0)?V[0][0]:(imin==1)?V[0][1]:(imin==2)?V[0][2]:V[0][3];
  double q1 = (imin==0)?V[1][0]:(imin==1)?V[1][1]:(imin==2)?V[1][2]:V[1][3];
  double q2 = (imin==0)?V[2][0]:(imin==1)?V[2][1]:(imin==2)?V[2][2]:V[2][3];
  double q3 = (imin==0)?V[3][0]:(imin==1)?V[3][1]:(imin==2)?V[3][2]:V[3][3];
  if (q0 < 0.0) { q0 = -q0; q1 = -q1; q2 = -q2; q3 = -q3; }
  out[4*b+0] = (float)q0; out[4*b+1] = (float)q1; out[4*b+2] = (float)q2; out[4*b+3] = (float)q3;
}

extern "C" void kernel_launch(void* const* d_in, const int* in_sizes, int n_in,
                              void* d_out, int out_size, void* d_ws, size_t ws_size,
                              hipStream_t stream) {
  (void)in_sizes; (void)n_in; (void)out_size; (void)ws_size;
  const float* x    = (const float*)d_in[0];
  const float* win1 = (const float*)d_in[1];
  const float* bin1 = (const float*)d_in[2];
  const float* g11  = (const float*)d_in[3];
  const float* wc1  = (const float*)d_in[5];
  const float* bc1  = (const float*)d_in[6];
  const float* g21  = (const float*)d_in[7];
  const float* wfc1 = (const float*)d_in[9];
  const float* bfc1 = (const float*)d_in[10];
  const float* win2 = (const float*)d_in[11];
  const float* bin2 = (const float*)d_in[12];
  const float* g12  = (const float*)d_in[13];
  const float* wc2  = (const float*)d_in[15];
  const float* bc2  = (const float*)d_in[16];
  const float* g22  = (const float*)d_in[17];
  const float* wfc2 = (const float*)d_in[19];
  const float* bfc2 = (const float*)d_in[20];
  const float* w1   = (const float*)d_in[21];
  const float* bh1  = (const float*)d_in[22];
  const float* gb1  = (const float*)d_in[23];
  const float* beb1 = (const float*)d_in[24];
  const float* w2   = (const float*)d_in[25];
  const float* bh2  = (const float*)d_in[26];
  const float* gb2  = (const float*)d_in[27];
  const float* beb2 = (const float*)d_in[28];
  const float* w3   = (const float*)d_in[29];
  const float* bh3  = (const float*)d_in[30];

  char* ws = (char*)d_ws;
  __half* h1  = (__half*)(ws + 0);                  // [2][256][128][1024] fp16 = 134,217,728 B
  float* rsB  = (float*)(ws + 134217728ULL);        // [2][256][128][2]
  float* xmom = (float*)(ws + 134742016ULL);        // [2][16]
  float* bn1a = (float*)(ws + 134742272ULL);        // [2][128][2]
  float* bn2a = (float*)(ws + 134744320ULL);        // [2][128][2]
  float* f    = (float*)(ws + 134746368ULL);        // [256][256]
  float* z1   = (float*)(ws + 135008512ULL);        // [256][256]
  float* bp1  = (float*)(ws + 135270656ULL);        // [256][2]
  float* z2   = (float*)(ws + 135272704ULL);        // [256][128]
  float* bp2  = (float*)(ws + 135403776ULL);        // [128][2]

  hipLaunchKernelGGL(k_init,     dim3(256), dim3(256), 0, stream, f, bfc1, bfc2, xmom, rsB);
  hipLaunchKernelGGL(k_xmom,     dim3(256), dim3(256), 0, stream, x, xmom);
  hipLaunchKernelGGL(k_bn1,      dim3(1),   dim3(256), 0, stream, xmom, win1, bin1, g11, win2, bin2, g12, bn1a);
  hipLaunchKernelGGL(k_h1,       dim3(512), dim3(256), 0, stream, x, win1, bin1, win2, bin2, bn1a, h1);
  hipLaunchKernelGGL(k_h2stats,  dim3(512), dim3(256), 0, stream, h1, wc1, bc1, wc2, bc2, rsB);
  hipLaunchKernelGGL(k_bn2,      dim3(256), dim3(256), 0, stream, rsB, g21, g22, bn2a);
  hipLaunchKernelGGL(k_hf,       dim3(512), dim3(256), 0, stream, h1, wc1, bc1, wc2, bc2, rsB, bn2a);
  hipLaunchKernelGGL(k_fgemm,    dim3(512), dim3(256), 0, stream, h1, wfc1, wfc2, f);
  hipLaunchKernelGGL(k_t1,       dim3(256), dim3(256), 0, stream, f, w1, bh1, z1);
  hipLaunchKernelGGL(k_colstats, dim3(256), dim3(256), 0, stream, z1, gb1, beb1, bp1, 256);
  hipLaunchKernelGGL(k_t3,       dim3(256), dim3(256), 0, stream, z1, bp1, w2, bh2, z2);
  hipLaunchKernelGGL(k_colstats, dim3(128), dim3(256), 0, stream, z2, gb2, beb2, bp2, 128);
  hipLaunchKernelGGL(k_t5,       dim3(1),   dim3(256), 0, stream, z2, bp2, w3, bh3, (float*)d_out);
}

// Round 4
// 530.346 us; speedup vs baseline: 3.1028x; 1.2977x over previous
//
#include <hip/hip_runtime.h>
#include <hip/hip_bf16.h>
#include <hip/hip_fp16.h>
#include <math.h>

#define EPSF 1e-5f

typedef _Float16 f16;
typedef __attribute__((ext_vector_type(8))) _Float16 f16x8;
typedef __attribute__((ext_vector_type(4))) float f32x4;
#define MFMA16(a, b, c) __builtin_amdgcn_mfma_f32_16x16x32_f16(a, b, c, 0, 0, 0)

// ---------------- K1: second moments of x per net -> per-block partials ----------------
__global__ __launch_bounds__(256) void k_xmom(const float* __restrict__ x, float* __restrict__ xpart) {
  int b = blockIdx.x, t = threadIdx.x, wid = t >> 6, lane = t & 63;
  const float* xr = x + (size_t)b * 6144;
  float a[18];
  #pragma unroll
  for (int i = 0; i < 18; ++i) a[i] = 0.f;
  #pragma unroll
  for (int net = 0; net < 2; ++net) {
    const float* xn = xr + net * 3072;
    float* ap = a + net * 9;
    for (int p = t; p < 1024; p += 256) {
      float x0 = xn[3*p], x1 = xn[3*p+1], x2 = xn[3*p+2];
      ap[0]+=x0; ap[1]+=x1; ap[2]+=x2;
      ap[3]+=x0*x0; ap[4]+=x0*x1; ap[5]+=x0*x2;
      ap[6]+=x1*x1; ap[7]+=x1*x2; ap[8]+=x2*x2;
    }
  }
  __shared__ float ls[4][18];
  #pragma unroll
  for (int i = 0; i < 18; ++i) {
    float v = a[i];
    #pragma unroll
    for (int m = 1; m < 64; m <<= 1) v += __shfl_xor(v, m, 64);
    if (lane == 0) ls[wid][i] = v;
  }
  __syncthreads();
  if (t < 18) xpart[b*20 + t] = ls[0][t] + ls[1][t] + ls[2][t] + ls[3][t];
}

// ---------------- K2: reduce partials + BN1 channel params (eps', sign) ----------------
__global__ __launch_bounds__(256) void k_bn1(const float* __restrict__ xpart,
                      const float* __restrict__ win1, const float* __restrict__ bin1, const float* __restrict__ g11,
                      const float* __restrict__ win2, const float* __restrict__ bin2, const float* __restrict__ g12,
                      float* __restrict__ bn1) {
  int t = threadIdx.x, wid = t >> 6, lane = t & 63;
  __shared__ float ls[4][18];
  __shared__ float xm[18];
  float v[18];
  #pragma unroll
  for (int i = 0; i < 18; ++i) v[i] = xpart[t*20 + i];
  #pragma unroll
  for (int i = 0; i < 18; ++i) {
    float r = v[i];
    #pragma unroll
    for (int m = 1; m < 64; m <<= 1) r += __shfl_xor(r, m, 64);
    if (lane == 0) ls[wid][i] = r;
  }
  __syncthreads();
  if (t < 18) xm[t] = ls[0][t] + ls[1][t] + ls[2][t] + ls[3][t];
  __syncthreads();
  int net = t >> 7, c = t & 127;
  const float* win = net ? win2 : win1;
  const float* bin = net ? bin2 : bin1;
  const float* g   = net ? g12  : g11;
  const float* m = xm + net * 9;
  const float inv = 1.f / (256.f * 1024.f);
  float w0 = win[3*c], w1 = win[3*c+1], w2 = win[3*c+2], bi = bin[c];
  float s0 = m[0]*inv, s1 = m[1]*inv, s2 = m[2]*inv;
  float lin = w0*s0 + w1*s1 + w2*s2;
  float mean = lin + bi;
  float e2 = (w0*w0*m[3] + 2.f*w0*w1*m[4] + 2.f*w0*w2*m[5] + w1*w1*m[6] + 2.f*w1*w2*m[7] + w2*w2*m[8]) * inv
             + 2.f*bi*lin + bi*bi;
  float var = fmaxf(e2 - mean*mean, 0.f);
  float gc = g[c];
  float aa = gc*gc / (var + EPSF);
  float sgn = (gc > 0.f) ? 1.f : ((gc < 0.f) ? -1.f : 0.f);
  float epsp = (aa > 0.f) ? (EPSF / aa) : 1.f;
  bn1[2*(net*128+c)]   = epsp;
  bn1[2*(net*128+c)+1] = sgn;
}

// ---------------- K3: h1 = relu(inorm(bn1(W_in x))) -> fp16 [cin][p] ----------------
__global__ __launch_bounds__(256) void k_h1(const float* __restrict__ x,
    const float* __restrict__ win1, const float* __restrict__ bin1,
    const float* __restrict__ win2, const float* __restrict__ bin2,
    const float* __restrict__ bn1, __half* __restrict__ h1) {
  int blk = blockIdx.x; int net = blk >> 8, b = blk & 255;
  int t = threadIdx.x, wid = t >> 6, lane = t & 63;
  __shared__ float xs[3072];
  const float4* xr = (const float4*)(x + (size_t)b*6144 + net*3072);
  float4* xsv = (float4*)xs;
  for (int i = t; i < 768; i += 256) xsv[i] = xr[i];
  __syncthreads();
  const float* win = net ? win2 : win1;
  const float* bin = net ? bin2 : bin1;
  __half* out = h1 + (size_t)(net*256 + b) * 131072;
  for (int c = wid; c < 128; c += 4) {
    float w0 = win[3*c], w1 = win[3*c+1], w2 = win[3*c+2], bi = bin[c];
    float h[16];
    float s = 0.f, ss = 0.f;
    #pragma unroll
    for (int j = 0; j < 8; ++j) {
      int base = 6*lane + 384*j;
      float2 d0 = *(const float2*)&xs[base];
      float2 d1 = *(const float2*)&xs[base+2];
      float2 d2 = *(const float2*)&xs[base+4];
      float v0 = w0*d0.x + w1*d0.y + w2*d1.x + bi;
      float v1 = w0*d1.y + w1*d2.x + w2*d2.y + bi;
      h[2*j] = v0; h[2*j+1] = v1;
      s += v0 + v1; ss += v0*v0 + v1*v1;
    }
    #pragma unroll
    for (int m = 1; m < 64; m <<= 1) { s += __shfl_xor(s, m, 64); ss += __shfl_xor(ss, m, 64); }
    float mean = s * (1.f/1024.f);
    float var  = fmaxf(ss * (1.f/1024.f) - mean*mean, 0.f);
    float epsp = bn1[2*(net*128+c)], sgn = bn1[2*(net*128+c)+1];
    float isd = sgn * rsqrtf(var + epsp);
    #pragma unroll
    for (int j = 0; j < 8; ++j) {
      float r0 = fmaxf((h[2*j]   - mean)*isd, 0.f);
      float r1 = fmaxf((h[2*j+1] - mean)*isd, 0.f);
      *(__half2*)(out + (size_t)c*1024 + 2*lane + 128*j) = __floats2half2_rn(r0, r1);
    }
  }
}

// ======= shared MFMA helpers for the 128x128 channel GEMM =======
__device__ __forceinline__ void stage_wc(char* sW, const float* wc, int t) {
  int cin8 = t & 15, cout0 = t >> 4;
  #pragma unroll
  for (int it = 0; it < 8; ++it) {
    int cout = cout0 + 16*it;
    const float* src = wc + cout*128 + cin8*8;
    float4 v0 = *(const float4*)src;
    float4 v1 = *(const float4*)(src + 4);
    f16x8 h = {(f16)v0.x,(f16)v0.y,(f16)v0.z,(f16)v0.w,(f16)v1.x,(f16)v1.y,(f16)v1.z,(f16)v1.w};
    *(f16x8*)(sW + cout*256 + ((cin8 ^ (cout & 7)) << 4)) = h;
  }
}

__device__ __forceinline__ void stage_btile(char* sB, const __half* h1b, int pch, int t) {
  int c = t & 63, pg0 = t >> 6;
  const __half* r0 = h1b + (size_t)(2*c)*1024 + pch*128;
  const __half* r1 = r0 + 1024;
  int sl = c >> 2;
  int ebyte = (c & 3) * 4;
  #pragma unroll
  for (int it = 0; it < 4; ++it) {
    int pg = pg0 + 4*it;
    uint4 ua = *(const uint4*)(r0 + pg*8);
    uint4 ub = *(const uint4*)(r1 + pg*8);
    unsigned A[4] = {ua.x, ua.y, ua.z, ua.w};
    unsigned B[4] = {ub.x, ub.y, ub.z, ub.w};
    #pragma unroll
    for (int j = 0; j < 8; ++j) {
      int p = pg*8 + j;
      unsigned lo = (A[j >> 1] >> ((j & 1) * 16)) & 0xffffu;
      unsigned hi = (B[j >> 1] >> ((j & 1) * 16)) & 0xffffu;
      *(unsigned*)(sB + sl*2048 + ((p ^ (sl & 7)) << 4) + ebyte) = lo | (hi << 16);
    }
  }
}

// ---------------- K4a: h2 row stats via MFMA (sum/sumsq per (b,cout)) ----------------
__global__ __launch_bounds__(256) void k_h2stats(const __half* __restrict__ h1,
    const float* __restrict__ wc1, const float* __restrict__ bc1,
    const float* __restrict__ wc2, const float* __restrict__ bc2,
    float* __restrict__ rs) {
  int blk = blockIdx.x; int net = blk >> 8, b = blk & 255;
  int t = threadIdx.x, wv = t >> 6, l = t & 63;
  __shared__ __align__(16) char sW[32768];
  __shared__ __align__(16) char sB[32768];
  const float* wc = net ? wc2 : wc1;
  const float* bc = net ? bc2 : bc1;
  stage_wc(sW, wc, t);
  __syncthreads();
  f16x8 afr[2][4];
  #pragma unroll
  for (int rt = 0; rt < 2; ++rt)
    #pragma unroll
    for (int kk = 0; kk < 4; ++kk) {
      int row = wv*32 + rt*16 + (l & 15);
      int cin8 = kk*4 + (l >> 4);
      afr[rt][kk] = *(const f16x8*)(sW + row*256 + ((cin8 ^ (row & 7)) << 4));
    }
  const __half* h1b = h1 + (size_t)(net*256 + b) * 131072;
  float sacc[2][4], qacc[2][4];
  #pragma unroll
  for (int rt = 0; rt < 2; ++rt)
    #pragma unroll
    for (int r = 0; r < 4; ++r) { sacc[rt][r] = 0.f; qacc[rt][r] = 0.f; }
  for (int pch = 0; pch < 8; ++pch) {
    __syncthreads();
    stage_btile(sB, h1b, pch, t);
    __syncthreads();
    #pragma unroll 2
    for (int pt = 0; pt < 8; ++pt) {
      f16x8 bf[4];
      #pragma unroll
      for (int kk = 0; kk < 4; ++kk) {
        int sl = kk*4 + (l >> 4);
        int p = pt*16 + (l & 15);
        bf[kk] = *(const f16x8*)(sB + sl*2048 + ((p ^ (sl & 7)) << 4));
      }
      f32x4 a0 = {0.f,0.f,0.f,0.f}, a1 = {0.f,0.f,0.f,0.f};
      #pragma unroll
      for (int kk = 0; kk < 4; ++kk) a0 = MFMA16(afr[0][kk], bf[kk], a0);
      #pragma unroll
      for (int kk = 0; kk < 4; ++kk) a1 = MFMA16(afr[1][kk], bf[kk], a1);
      #pragma unroll
      for (int r = 0; r < 4; ++r) {
        sacc[0][r] += a0[r]; qacc[0][r] += a0[r]*a0[r];
        sacc[1][r] += a1[r]; qacc[1][r] += a1[r]*a1[r];
      }
    }
  }
  #pragma unroll
  for (int rt = 0; rt < 2; ++rt)
    #pragma unroll
    for (int r = 0; r < 4; ++r) {
      float s = sacc[rt][r], q = qacc[rt][r];
      #pragma unroll
      for (int m = 1; m < 16; m <<= 1) { s += __shfl_xor(s, m, 64); q += __shfl_xor(q, m, 64); }
      if ((l & 15) == 0) {
        int row = wv*32 + rt*16 + ((l >> 4) << 2) + r;
        float bi = bc[row];
        float s2 = s + 1024.f*bi;
        float q2 = q + 2.f*bi*s + 1024.f*bi*bi;
        float* dst = rs + (size_t)(net*256 + b) * 256 + 2*row;
        dst[0] = s2;
        dst[1] = q2;
      }
    }
}

// ---------------- K5: BN2 channel params from rowstats (parallel) ----------------
__global__ void k_bn2(const float* __restrict__ rs,
                      const float* __restrict__ g21, const float* __restrict__ g22,
                      float* __restrict__ bn2) {
  int blk = blockIdx.x;  // 256: net*128+c
  int net = blk >> 7, c = blk & 127;
  int t = threadIdx.x;   // b
  const float* p = rs + (size_t)(net*256 + t) * 256 + 2*c;
  float s = p[0], q = p[1];
  #pragma unroll
  for (int m = 1; m < 64; m <<= 1) { s += __shfl_xor(s, m, 64); q += __shfl_xor(q, m, 64); }
  __shared__ float ss[4], qq[4];
  if ((t & 63) == 0) { ss[t >> 6] = s; qq[t >> 6] = q; }
  __syncthreads();
  if (t == 0) {
    s = ss[0] + ss[1] + ss[2] + ss[3];
    q = qq[0] + qq[1] + qq[2] + qq[3];
    const float inv = 1.f / (256.f * 1024.f);
    float mean = s * inv;
    float var = fmaxf(q*inv - mean*mean, 0.f);
    float gc = (net ? g22 : g21)[c];
    float aa = gc*gc / (var + EPSF);
    float sgn = (gc > 0.f) ? 1.f : ((gc < 0.f) ? -1.f : 0.f);
    float epsp = (aa > 0.f) ? (EPSF / aa) : 1.f;
    bn2[2*(net*128+c)]   = epsp;
    bn2[2*(net*128+c)+1] = sgn;
  }
}

// ---------------- K4b: recompute h2 via MFMA, hf = relu(inorm(h2)) + h1 in place ----------------
__global__ __launch_bounds__(256) void k_hf(__half* __restrict__ h1,
    const float* __restrict__ wc1, const float* __restrict__ bc1,
    const float* __restrict__ wc2, const float* __restrict__ bc2,
    const float* __restrict__ rs, const float* __restrict__ bn2) {
  int blk = blockIdx.x; int net = blk >> 8, b = blk & 255;
  int t = threadIdx.x, wv = t >> 6, l = t & 63;
  __shared__ __align__(16) char sW[32768];
  __shared__ __align__(16) char sB[32768];
  const float* wc = net ? wc2 : wc1;
  const float* bc = net ? bc2 : bc1;
  stage_wc(sW, wc, t);
  __syncthreads();
  f16x8 afr[2][4];
  #pragma unroll
  for (int rt = 0; rt < 2; ++rt)
    #pragma unroll
    for (int kk = 0; kk < 4; ++kk) {
      int row = wv*32 + rt*16 + (l & 15);
      int cin8 = kk*4 + (l >> 4);
      afr[rt][kk] = *(const f16x8*)(sW + row*256 + ((cin8 ^ (row & 7)) << 4));
    }
  float mup[2][4], al[2][4];
  #pragma unroll
  for (int rt = 0; rt < 2; ++rt)
    #pragma unroll
    for (int r = 0; r < 4; ++r) {
      int row = wv*32 + rt*16 + ((l >> 4) << 2) + r;
      const float* pp = rs + (size_t)(net*256 + b) * 256 + 2*row;
      float sv = pp[0], qv = pp[1];
      float m = sv * (1.f/1024.f);
      float var = fmaxf(qv * (1.f/1024.f) - m*m, 0.f);
      float ep = bn2[2*(net*128+row)], sg = bn2[2*(net*128+row)+1];
      al[rt][r] = sg * rsqrtf(var + ep);
      mup[rt][r] = m - bc[row];
    }
  __half* h1b = h1 + (size_t)(net*256 + b) * 131072;
  for (int pch = 0; pch < 8; ++pch) {
    __syncthreads();
    stage_btile(sB, h1b, pch, t);
    __syncthreads();
    #pragma unroll 2
    for (int pt = 0; pt < 8; ++pt) {
      f16x8 bf[4];
      #pragma unroll
      for (int kk = 0; kk < 4; ++kk) {
        int sl = kk*4 + (l >> 4);
        int p = pt*16 + (l & 15);
        bf[kk] = *(const f16x8*)(sB + sl*2048 + ((p ^ (sl & 7)) << 4));
      }
      f32x4 a0 = {0.f,0.f,0.f,0.f}, a1 = {0.f,0.f,0.f,0.f};
      #pragma unroll
      for (int kk = 0; kk < 4; ++kk) a0 = MFMA16(afr[0][kk], bf[kk], a0);
      #pragma unroll
      for (int kk = 0; kk < 4; ++kk) a1 = MFMA16(afr[1][kk], bf[kk], a1);
      int prel = pt*16 + (l & 15);
      #pragma unroll
      for (int rt = 0; rt < 2; ++rt) {
        f32x4 av = rt ? a1 : a0;
        #pragma unroll
        for (int r = 0; r < 4; ++r) {
          int row = wv*32 + rt*16 + ((l >> 4) << 2) + r;
          int sl2 = row >> 3, e2 = row & 7;
          float resid = __half2float(*(const __half*)(sB + sl2*2048 + ((prel ^ (sl2 & 7)) << 4) + e2*2));
          float v = fmaxf((av[r] - mup[rt][r]) * al[rt][r], 0.f) + resid;
          h1b[(size_t)row*1024 + pch*128 + prel] = __float2half(v);
        }
      }
    }
  }
}

// ---------------- K6: fpart[ks] = hf @ wfc^T partial (no atomics) ----------------
__global__ __launch_bounds__(512) void k_fgemm(const __half* __restrict__ hf,
    const float* __restrict__ wfc1, const float* __restrict__ wfc2,
    float* __restrict__ fpart) {
  int bid = blockIdx.x;                 // 256 = 2 net x 2 bt x 64 ks
  int net = bid >> 7;
  int bt  = (bid >> 6) & 1;
  int ks  = bid & 63;
  int t = threadIdx.x, wv = t >> 6, l = t & 63;
  __shared__ __align__(16) char sA[8192];   // 128 b x 32 k fp16, swizzled
  __shared__ __align__(16) char sW[8192];   // 128 o x 32 k fp16, swizzled
  const float* wfc = net ? wfc2 : wfc1;
  int b0 = bt * 128;
  size_t kbase = (size_t)ks * 2048;
  f32x4 acc[8];
  #pragma unroll
  for (int ot = 0; ot < 8; ++ot) acc[ot] = (f32x4){0.f,0.f,0.f,0.f};
  const __half* hfb = hf + (size_t)(net*256 + b0) * 131072 + kbase;
  for (int step = 0; step < 64; ++step) {
    __syncthreads();
    {
      int bb = t >> 2, k8 = t & 3;
      uint4 v = *(const uint4*)(hfb + (size_t)bb * 131072 + step*32 + k8*8);
      *(uint4*)(sA + bb*64 + ((k8 ^ ((bb >> 1) & 3)) << 4)) = v;
    }
    {
      int o = t >> 2, k8 = t & 3;
      const float* src = wfc + (size_t)o * 131072 + kbase + step*32 + k8*8;
      float4 v0 = *(const float4*)src;
      float4 v1 = *(const float4*)(src + 4);
      f16x8 h = {(f16)v0.x,(f16)v0.y,(f16)v0.z,(f16)v0.w,(f16)v1.x,(f16)v1.y,(f16)v1.z,(f16)v1.w};
      *(f16x8*)(sW + o*64 + ((k8 ^ ((o >> 1) & 3)) << 4)) = h;
    }
    __syncthreads();
    int bb = wv*16 + (l & 15), k8 = l >> 4;
    f16x8 a = *(const f16x8*)(sA + bb*64 + ((k8 ^ ((bb >> 1) & 3)) << 4));
    #pragma unroll
    for (int ot = 0; ot < 8; ++ot) {
      int o = ot*16 + (l & 15);
      f16x8 bfr = *(const f16x8*)(sW + o*64 + ((k8 ^ ((o >> 1) & 3)) << 4));
      acc[ot] = MFMA16(a, bfr, acc[ot]);
    }
  }
  float* fp = fpart + (size_t)ks * 65536;
  #pragma unroll
  for (int ot = 0; ot < 8; ++ot) {
    int col = net*128 + ot*16 + (l & 15);
    #pragma unroll
    for (int r = 0; r < 4; ++r) {
      int row = b0 + wv*16 + ((l >> 4) << 2) + r;
      fp[(size_t)row*256 + col] = acc[ot][r];
    }
  }
}

// ---------------- tail: reduce fpart + bias, z1 = y @ w1^T + bh1 ----------------
__global__ __launch_bounds__(256) void k_t1(const float* __restrict__ fpart,
                                            const float* __restrict__ bfc1, const float* __restrict__ bfc2,
                                            const float* __restrict__ w1,
                                            const float* __restrict__ bh1, float* __restrict__ z1) {
  int b = blockIdx.x, t = threadIdx.x, wid = t >> 6, lane = t & 63;
  __shared__ float ys[256];
  float acc = (t < 128) ? bfc1[t] : bfc2[t - 128];
  const float* fp = fpart + (size_t)b*256 + t;
  #pragma unroll 8
  for (int ks = 0; ks < 64; ++ks) acc += fp[(size_t)ks * 65536];
  ys[t] = acc;
  __syncthreads();
  for (int j = wid; j < 256; j += 4) {
    const float* wr = w1 + j*256;
    float a = ys[lane]*wr[lane] + ys[lane+64]*wr[lane+64] + ys[lane+128]*wr[lane+128] + ys[lane+192]*wr[lane+192];
    #pragma unroll
    for (int m = 1; m < 64; m <<= 1) a += __shfl_xor(a, m, 64);
    if (lane == 0) z1[b*256 + j] = a + bh1[j];
  }
}

// ---------------- tail: per-column batch stats (parallel) ----------------
__global__ void k_colstats(const float* __restrict__ z, const float* __restrict__ g,
                           const float* __restrict__ be, float* __restrict__ bp, int ncols) {
  int j = blockIdx.x, t = threadIdx.x;
  float v = z[(size_t)t * ncols + j];
  float s = v, q = v*v;
  #pragma unroll
  for (int m = 1; m < 64; m <<= 1) { s += __shfl_xor(s, m, 64); q += __shfl_xor(q, m, 64); }
  __shared__ float ss[4], qq[4];
  if ((t & 63) == 0) { ss[t >> 6] = s; qq[t >> 6] = q; }
  __syncthreads();
  if (t == 0) {
    s = ss[0] + ss[1] + ss[2] + ss[3];
    q = qq[0] + qq[1] + qq[2] + qq[3];
    float mean = s * (1.f/256.f);
    float var = fmaxf(q * (1.f/256.f) - mean*mean, 0.f);
    float sc = g[j] * rsqrtf(var + EPSF);
    bp[2*j] = sc; bp[2*j+1] = be[j] - mean*sc;
  }
}

// ---------------- tail: z2 = relu(bn(z1)) @ w2^T + bh2 ----------------
__global__ __launch_bounds__(256) void k_t3(const float* __restrict__ z1, const float* __restrict__ bp1,
                                            const float* __restrict__ w2, const float* __restrict__ bh2,
                                            float* __restrict__ z2) {
  int b = blockIdx.x, t = threadIdx.x, wid = t >> 6, lane = t & 63;
  __shared__ float ys[256];
  ys[t] = fmaxf(z1[b*256 + t]*bp1[2*t] + bp1[2*t+1], 0.f);
  __syncthreads();
  for (int j = wid; j < 128; j += 4) {
    const float* wr = w2 + j*256;
    float a = ys[lane]*wr[lane] + ys[lane+64]*wr[lane+64] + ys[lane+128]*wr[lane+128] + ys[lane+192]*wr[lane+192];
    #pragma unroll
    for (int m = 1; m < 64; m <<= 1) a += __shfl_xor(a, m, 64);
    if (lane == 0) z2[b*128 + j] = a + bh2[j];
  }
}

// ---------------- tail: y3 + symmetric 4x4 Jacobi eigensolver ----------------
__global__ __launch_bounds__(256) void k_t5(const float* __restrict__ z2, const float* __restrict__ bp2,
                                            const float* __restrict__ w3, const float* __restrict__ bh3,
                                            float* __restrict__ out) {
  __shared__ float w3s[2048];
  __shared__ float sc[128], sh[128], b3[16];
  int t = threadIdx.x;
  for (int i = t; i < 2048; i += 256) w3s[i] = w3[i];
  if (t < 128) { sc[t] = bp2[2*t]; sh[t] = bp2[2*t+1]; }
  if (t < 16) b3[t] = bh3[t];
  __syncthreads();
  int b = t;
  float r[128];
  #pragma unroll
  for (int i = 0; i < 128; i += 4) {
    float4 v = *(const float4*)(z2 + b*128 + i);
    r[i]   = fmaxf(v.x*sc[i]   + sh[i],   0.f);
    r[i+1] = fmaxf(v.y*sc[i+1] + sh[i+1], 0.f);
    r[i+2] = fmaxf(v.z*sc[i+2] + sh[i+2], 0.f);
    r[i+3] = fmaxf(v.w*sc[i+3] + sh[i+3], 0.f);
  }
  float y3[16];
  #pragma unroll
  for (int j = 0; j < 16; ++j) {
    float a = b3[j];
    #pragma unroll
    for (int i = 0; i < 128; ++i) a += r[i]*w3s[j*128 + i];
    y3[j] = a;
  }
  double A[4][4], V[4][4];
  #pragma unroll
  for (int i2 = 0; i2 < 4; ++i2)
    #pragma unroll
    for (int j2 = 0; j2 < 4; ++j2) {
      A[i2][j2] = 0.5 * ((double)y3[4*i2 + j2] + (double)y3[4*j2 + i2]);
      V[i2][j2] = (i2 == j2) ? 1.0 : 0.0;
    }
  for (int sweep = 0; sweep < 12; ++sweep) {
    #pragma unroll
    for (int pi = 0; pi < 6; ++pi) {
      const int PP[6] = {0,0,0,1,1,2};
      const int QQ[6] = {1,2,3,2,3,3};
      int p = PP[pi], q = QQ[pi];
      double apq = A[p][q];
      if (fabs(apq) > 1e-300) {
        double tau = (A[q][q] - A[p][p]) / (2.0 * apq);
        double tt = (tau >= 0.0 ? 1.0 : -1.0) / (fabs(tau) + sqrt(1.0 + tau*tau));
        double cc = 1.0 / sqrt(1.0 + tt*tt);
        double sn = tt * cc;
        #pragma unroll
        for (int k2 = 0; k2 < 4; ++k2) {
          double akp = A[k2][p], akq = A[k2][q];
          A[k2][p] = cc*akp - sn*akq;
          A[k2][q] = sn*akp + cc*akq;
        }
        #pragma unroll
        for (int k2 = 0; k2 < 4; ++k2) {
          double apk = A[p][k2], aqk = A[q][k2];
          A[p][k2] = cc*apk - sn*aqk;
          A[q][k2] = sn*apk + cc*aqk;
        }
        #pragma unroll
        for (int k2 = 0; k2 < 4; ++k2) {
          double vkp = V[k2][p], vkq = V[k2][q];
          V[k2][p] = cc*vkp - sn*vkq;
          V[k2][q] = sn*vkp + cc*vkq;
        }
      }
    }
  }
  int imin = 0; double mv = A[0][0];
  if (A[1][1] < mv) { mv = A[1][1]; imin = 1; }
  if (A[2][2] < mv) { mv = A[2][2]; imin = 2; }
  if (A[3][3] < mv) { mv = A[3][3]; imin = 3; }
  double q0 = (imin==0)?V[0][0]:(imin==1)?V[0][1]:(imin==2)?V[0][2]:V[0][3];
  double q1 = (imin==0)?V[1][0]:(imin==1)?V[1][1]:(imin==2)?V[1][2]:V[1][3];
  double q2 = (imin==0)?V[2][0]:(imin==1)?V[2][1]:(imin==2)?V[2][2]:V[2][3];
  double q3 = (imin==0)?V[3][0]:(imin==1)?V[3][1]:(imin==2)?V[3][2]:V[3][3];
  if (q0 < 0.0) { q0 = -q0; q1 = -q1; q2 = -q2; q3 = -q3; }
  out[4*b+0] = (float)q0; out[4*b+1] = (float)q1; out[4*b+2] = (float)q2; out[4*b+3] = (float)q3;
}

extern "C" void kernel_launch(void* const* d_in, const int* in_sizes, int n_in,
                              void* d_out, int out_size, void* d_ws, size_t ws_size,
                              hipStream_t stream) {
  (void)in_sizes; (void)n_in; (void)out_size; (void)ws_size;
  const float* x    = (const float*)d_in[0];
  const float* win1 = (const float*)d_in[1];
  const float* bin1 = (const float*)d_in[2];
  const float* g11  = (const float*)d_in[3];
  const float* wc1  = (const float*)d_in[5];
  const float* bc1  = (const float*)d_in[6];
  const float* g21  = (const float*)d_in[7];
  const float* wfc1 = (const float*)d_in[9];
  const float* bfc1 = (const float*)d_in[10];
  const float* win2 = (const float*)d_in[11];
  const float* bin2 = (const float*)d_in[12];
  const float* g12  = (const float*)d_in[13];
  const float* wc2  = (const float*)d_in[15];
  const float* bc2  = (const float*)d_in[16];
  const float* g22  = (const float*)d_in[17];
  const float* wfc2 = (const float*)d_in[19];
  const float* bfc2 = (const float*)d_in[20];
  const float* w1   = (const float*)d_in[21];
  const float* bh1  = (const float*)d_in[22];
  const float* gb1  = (const float*)d_in[23];
  const float* beb1 = (const float*)d_in[24];
  const float* w2   = (const float*)d_in[25];
  const float* bh2  = (const float*)d_in[26];
  const float* gb2  = (const float*)d_in[27];
  const float* beb2 = (const float*)d_in[28];
  const float* w3   = (const float*)d_in[29];
  const float* bh3  = (const float*)d_in[30];

  char* ws = (char*)d_ws;
  __half* h1   = (__half*)(ws + 0);                  // [2][256][128][1024] fp16 = 134,217,728 B
  float* rsB   = (float*)(ws + 134217728ULL);        // [2][256][128][2] = 524,288 B
  float* bn1a  = (float*)(ws + 134742016ULL);        // [2][128][2]
  float* bn2a  = (float*)(ws + 134744064ULL);        // [2][128][2]
  float* fpart = (float*)(ws + 134746112ULL);        // [64][256][256] = 16,777,216 B
  float* xpart = (float*)(ws + 151523328ULL);        // [256][20]
  float* z1    = (float*)(ws + 151543808ULL);        // [256][256]
  float* bp1   = (float*)(ws + 151805952ULL);        // [256][2]
  float* z2    = (float*)(ws + 151808000ULL);        // [256][128]
  float* bp2   = (float*)(ws + 151939072ULL);        // [128][2]

  hipLaunchKernelGGL(k_xmom,     dim3(256), dim3(256), 0, stream, x, xpart);
  hipLaunchKernelGGL(k_bn1,      dim3(1),   dim3(256), 0, stream, xpart, win1, bin1, g11, win2, bin2, g12, bn1a);
  hipLaunchKernelGGL(k_h1,       dim3(512), dim3(256), 0, stream, x, win1, bin1, win2, bin2, bn1a, h1);
  hipLaunchKernelGGL(k_h2stats,  dim3(512), dim3(256), 0, stream, h1, wc1, bc1, wc2, bc2, rsB);
  hipLaunchKernelGGL(k_bn2,      dim3(256), dim3(256), 0, stream, rsB, g21, g22, bn2a);
  hipLaunchKernelGGL(k_hf,       dim3(512), dim3(256), 0, stream, h1, wc1, bc1, wc2, bc2, rsB, bn2a);
  hipLaunchKernelGGL(k_fgemm,    dim3(256), dim3(512), 0, stream, h1, wfc1, wfc2, fpart);
  hipLaunchKernelGGL(k_t1,       dim3(256), dim3(256), 0, stream, fpart, bfc1, bfc2, w1, bh1, z1);
  hipLaunchKernelGGL(k_colstats, dim3(256), dim3(256), 0, stream, z1, gb1, beb1, bp1, 256);
  hipLaunchKernelGGL(k_t3,       dim3(256), dim3(256), 0, stream, z1, bp1, w2, bh2, z2);
  hipLaunchKernelGGL(k_colstats, dim3(128), dim3(256), 0, stream, z2, gb2, beb2, bp2, 128);
  hipLaunchKernelGGL(k_t5,       dim3(1),   dim3(256), 0, stream, z2, bp2, w3, bh3, (float*)d_out);
}